// Round 5
// baseline (140.912 us; speedup 1.0000x reference)
//
#include <hip/hip_runtime.h>
#include <hip/hip_bf16.h>

#define BB 8
#define NN 2000
#define VV 2000
#define KK 100
#define EMB 128
#define PENALTY -1e9f
#define NBIN 512            // tracked bins; bin = v*2048 clamped to 511
#define BINSCALE 2048.0f
#define CAP 200
#define XPAD 224   // 201 padded to 7*32

typedef __attribute__((ext_vector_type(8))) short short8;
typedef __attribute__((ext_vector_type(4))) float f32x4;

__device__ __forceinline__ unsigned short bf16rne(float f) {
    unsigned u = __float_as_uint(f);
    u += 0x7FFF + ((u >> 16) & 1);
    return (unsigned short)(u >> 16);
}
__device__ __forceinline__ float bf2f(unsigned short s) {
    return __uint_as_float((unsigned)s << 16);
}

// ---------------------------------------------------------------------------
// Kernel 0: pack weights into MFMA B-fragment layout, bf16.
// ---------------------------------------------------------------------------
__global__ __launch_bounds__(256) void wpack_kernel(
    const float* __restrict__ w1, const float* __restrict__ w2,
    const float* __restrict__ w3, const float* __restrict__ w4,
    unsigned short* __restrict__ pw1, unsigned short* __restrict__ pw2,
    unsigned short* __restrict__ pw3, unsigned short* __restrict__ pw4)
{
    const int bt = blockIdx.x;   // 0..211
    const int t = threadIdx.x;
    for (int e = t; e < 512; e += 256) {
        int lane = e >> 3, j = e & 7;
        int kk = ((lane >> 4) << 3) + j;   // 0..31
        int nn = lane & 15;
        if (bt < 56) {                     // pw1: K=201, N=128
            int kt = bt >> 3, nt = bt & 7;
            int k = kt * 32 + kk, n = nt * 16 + nn;
            float f = (k < 201) ? w1[k * 128 + n] : 0.f;
            pw1[bt * 512 + e] = bf16rne(f);
        } else if (bt < 120) {             // pw2: K=128, N=256
            int bb = bt - 56, kt = bb >> 4, nt = bb & 15;
            pw2[bb * 512 + e] = bf16rne(w2[(kt * 32 + kk) * 256 + nt * 16 + nn]);
        } else if (bt < 184) {             // pw3: K=256, N=128
            int bb = bt - 120, kt = bb >> 3, nt = bb & 7;
            pw3[bb * 512 + e] = bf16rne(w3[(kt * 32 + kk) * 128 + nt * 16 + nn]);
        } else {                           // pw4: K=128, N=100->112
            int bb = bt - 184, kt = bb / 7, nt = bb % 7;
            int n = nt * 16 + nn;
            float f = (n < 100) ? w4[(kt * 32 + kk) * 100 + n] : 0.f;
            pw4[bb * 512 + e] = bf16rne(f);
        }
    }
}

// ---------------------------------------------------------------------------
// Kernel 1: per-row exact top-K (ascending, ties by index).
// 512 tracked bins (width 1/2048, clamp bin 511 skipped in histogram —
// values there can't be winners unless the threshold bin is 511, which
// triggers the exact radix fallback). Prefix scan 2 bins/thread, bin-sorted
// scatter, odd-even fix-up. Writes xin bf16 [M][224].
// ---------------------------------------------------------------------------
__global__ __launch_bounds__(256) void topk_kernel(
    const float* __restrict__ dist, const float* __restrict__ theta,
    const float* __restrict__ scale,
    unsigned short* __restrict__ xin, float* __restrict__ sdist,
    int* __restrict__ idxb)
{
    __shared__ __align__(16) unsigned hist[NBIN];
    __shared__ unsigned long long comp[CAP];
    __shared__ unsigned wsum[4];
    __shared__ int sh_Bt, sh_m, sh_mult;
    __shared__ int sh_cnt, sh_ntie, sh_kth;
    __shared__ unsigned sh_pref;
    __shared__ int sh_tie[64];
    __shared__ float sh_Tf;

    const int row = blockIdx.x;
    const int t = threadIdx.x;
    const int lane = t & 63, wid = t >> 6;
    const float* drow = dist + (size_t)row * VV;

    unsigned kb[8];
    int bn[8];
    if (t < VV / 8) {
        const float4* d4 = (const float4*)drow;
        float4 a = d4[t * 2], b2 = d4[t * 2 + 1];
        float vv[8] = {a.x, a.y, a.z, a.w, b2.x, b2.y, b2.z, b2.w};
#pragma unroll
        for (int j = 0; j < 8; ++j) {
            kb[j] = __float_as_uint(vv[j]);
            int b = (int)(vv[j] * BINSCALE);
            bn[j] = b < 0 ? 0 : (b > NBIN - 1 ? NBIN - 1 : b);
        }
    } else {
#pragma unroll
        for (int j = 0; j < 8; ++j) { kb[j] = 0xFFFFFFFFu; bn[j] = NBIN - 1; }
    }

    hist[t] = 0u;
    hist[t + 256] = 0u;
    if (t == 0) { sh_cnt = 0; sh_ntie = 0; sh_mult = 1; sh_Bt = NBIN - 1; sh_m = 100000; }
    __syncthreads();
#pragma unroll
    for (int j = 0; j < 8; ++j)
        if (bn[j] < NBIN - 1) atomicAdd(&hist[bn[j]], 1u);
    __syncthreads();

    // ---- prefix over 512 bins: thread t owns bins {2t, 2t+1} ----
    uint2 cc = *(const uint2*)&hist[2 * t];
    const unsigned c0 = cc.x, c1 = cc.y;
    const unsigned tot = c0 + c1;
    unsigned incl = tot;
#pragma unroll
    for (int off = 1; off < 64; off <<= 1) {
        unsigned v = __shfl_up(incl, (unsigned)off);
        if (lane >= off) incl += v;
    }
    if (lane == 63) wsum[wid] = incl;
    __syncthreads();
    unsigned woff = 0;
    for (int w = 0; w < wid; ++w) woff += wsum[w];
    const unsigned excl = woff + incl - tot;
    const unsigned run = excl + tot;

    { uint2 off2; off2.x = excl; off2.y = excl + c0; *(uint2*)&hist[2 * t] = off2; }
    if (excl < KK && excl + c0 >= KK) {
        sh_Bt = 2 * t; sh_m = (int)(excl + c0);
    } else if (t < 255 && excl + c0 < KK && run >= KK) {
        sh_Bt = 2 * t + 1; sh_m = (int)run;
    }
    __syncthreads();
    const int Bt = sh_Bt;
    const int m = sh_m;

    {
        int mx = 0;
        if (2 * t <= Bt) mx = (int)c0;
        if (2 * t + 1 <= Bt) mx = mx > (int)c1 ? mx : (int)c1;
        if (mx > 1) atomicMax(&sh_mult, mx);
    }

    if (m <= CAP) {
#pragma unroll
        for (int j = 0; j < 8; ++j) {
            if (bn[j] <= Bt) {
                int slot = (int)atomicAdd(&hist[bn[j]], 1u);
                comp[slot] = ((unsigned long long)kb[j] << 32) | (unsigned)(t * 8 + j);
            }
        }
        __syncthreads();
        const int passes = (sh_mult > 1) ? sh_mult + 1 : 0;
        for (int p = 0; p < passes; ++p) {
            int i = 2 * t + (p & 1);
            if (i + 1 < m) {
                unsigned long long a = comp[i], b2 = comp[i + 1];
                if (a > b2) { comp[i] = b2; comp[i + 1] = a; }
            }
            __syncthreads();
        }
        const float Tf = __uint_as_float((unsigned)(comp[KK - 1] >> 32));
        const float invT = 1.0f / Tf;
        const float* trow = theta + (size_t)row * VV;
        if (t < KK) {
            unsigned long long c = comp[t];
            unsigned kbits = (unsigned)(c >> 32);
            int id = (int)(c & 0xFFFFFFFFu);
            float nv = __uint_as_float(kbits) * invT;
            xin[(size_t)row * XPAD + t] = bf16rne(nv);
            xin[(size_t)row * XPAD + 100 + t] = bf16rne(trow[id]);
            sdist[(size_t)row * KK + t] = nv;
            idxb[(size_t)row * KK + t] = id;
        }
        if (t == 255) xin[(size_t)row * XPAD + 200] = bf16rne(scale[row]);
    } else {
        // ---------- rare fallback: exact radix-refine of the threshold bucket
        // (also covers the "threshold in clamp bin" case, Bt = 511) ----------
#pragma unroll
        for (int j = 0; j < 8; ++j) {
            if (bn[j] < Bt) {
                int pos = atomicAdd(&sh_cnt, 1);
                if (pos < CAP)
                    comp[pos] = ((unsigned long long)kb[j] << 32) | (unsigned)(t * 8 + j);
            }
        }
        __syncthreads();
        int nless = sh_cnt;
        if (t == 0) { sh_pref = 0u; sh_kth = KK - nless; }
        __syncthreads();
        for (int p = 0; p < 4; ++p) {
            if (t < 256) hist[t] = 0u;
            __syncthreads();
            const int shift = 24 - 8 * p;
            const unsigned pref = sh_pref;
#pragma unroll
            for (int j = 0; j < 8; ++j) {
                if (bn[j] == Bt) {
                    unsigned k = kb[j];
                    bool ok = (p == 0) || ((k >> (shift + 8)) == pref);
                    if (ok) atomicAdd(&hist[(k >> shift) & 255u], 1u);
                }
            }
            __syncthreads();
            if (t == 0) {
                int kth = sh_kth;
                unsigned cum = 0;
                int b = 0;
                for (; b < 256; ++b) {
                    unsigned c = hist[b];
                    if (cum + c >= (unsigned)kth) break;
                    cum += c;
                }
                sh_pref = (pref << 8) | (unsigned)b;
                sh_kth = kth - (int)cum;
            }
            __syncthreads();
        }
        const unsigned T = sh_pref;
        const int need2 = sh_kth;
#pragma unroll
        for (int j = 0; j < 8; ++j) {
            if (bn[j] == Bt) {
                unsigned k = kb[j];
                if (k < T) {
                    int pos = atomicAdd(&sh_cnt, 1);
                    if (pos < CAP)
                        comp[pos] = ((unsigned long long)k << 32) | (unsigned)(t * 8 + j);
                } else if (k == T) {
                    int q = atomicAdd(&sh_ntie, 1);
                    if (q < 64) sh_tie[q] = t * 8 + j;
                }
            }
        }
        __syncthreads();
        if (t == 0) {
            int nl2 = sh_cnt;
            int nt = sh_ntie < 64 ? sh_ntie : 64;
            for (int i = 1; i < nt; ++i) {
                int v = sh_tie[i], j2 = i - 1;
                while (j2 >= 0 && sh_tie[j2] > v) { sh_tie[j2 + 1] = sh_tie[j2]; --j2; }
                sh_tie[j2 + 1] = v;
            }
            for (int i = 0; i < need2; ++i)
                comp[nl2 + i] = ((unsigned long long)T << 32) | (unsigned)sh_tie[i];
            sh_cnt = nl2 + need2;
        }
        __syncthreads();
        const int mm = sh_cnt;
        unsigned long long c = (t < mm) ? comp[t] : ~0ull;
        int rank = 0;
        if (t < mm) {
            for (int j = 0; j < mm; ++j) {
                unsigned long long cj = comp[j];
                rank += (cj < c) || (cj == c && j < t);
            }
            if (rank == KK - 1) sh_Tf = __uint_as_float((unsigned)(c >> 32));
        }
        __syncthreads();
        const float invT = 1.0f / sh_Tf;
        const float* trow = theta + (size_t)row * VV;
        if (t < mm && rank < KK) {
            unsigned kbits = (unsigned)(c >> 32);
            int id = (int)(c & 0xFFFFFFFFu);
            float nv = __uint_as_float(kbits) * invT;
            xin[(size_t)row * XPAD + rank] = bf16rne(nv);
            xin[(size_t)row * XPAD + 100 + rank] = bf16rne(trow[id]);
            sdist[(size_t)row * KK + rank] = nv;
            idxb[(size_t)row * KK + rank] = id;
        }
        if (t == 255) xin[(size_t)row * XPAD + 200] = bf16rne(scale[row]);
    }
}

// ---------------------------------------------------------------------------
// Kernel 2: fused layers 1+2 via MFMA. Block = 64 rows, 4 waves.
// ---------------------------------------------------------------------------
__global__ __launch_bounds__(256) void fused12_mfma(
    const unsigned short* __restrict__ xin, const unsigned short* __restrict__ pw1,
    const float* __restrict__ b1, const unsigned short* __restrict__ pw2,
    const float* __restrict__ b2, unsigned short* __restrict__ h)
{
    __shared__ unsigned short c1s[64][136];
    const int t = threadIdx.x;
    const int w = t >> 6, l = t & 63;
    const int m0 = blockIdx.x * 64;
    const int lr = l & 15, lg = l >> 4;

    f32x4 acc[8] = {};
    const short8* arow = (const short8*)(xin + (size_t)(m0 + 16 * w + lr) * XPAD);
    const short8* pw1v = (const short8*)pw1;
#pragma unroll
    for (int kt = 0; kt < 7; ++kt) {
        short8 a = arow[kt * 4 + lg];
#pragma unroll
        for (int nt = 0; nt < 8; ++nt) {
            short8 b = pw1v[(kt * 8 + nt) * 64 + l];
            acc[nt] = __builtin_amdgcn_mfma_f32_16x16x32_bf16(a, b, acc[nt], 0, 0, 0);
        }
    }
#pragma unroll
    for (int nt = 0; nt < 8; ++nt) {
        int col = nt * 16 + lr;
        float bb = b1[col];
#pragma unroll
        for (int r = 0; r < 4; ++r) {
            float v = fmaxf(acc[nt][r] + bb, 0.f);
            c1s[16 * w + lg * 4 + r][col] = bf16rne(v);
        }
    }
    __syncthreads();

    f32x4 acc2[16] = {};
    const short8* pw2v = (const short8*)pw2;
#pragma unroll
    for (int kt = 0; kt < 4; ++kt) {
        short8 a = *(const short8*)&c1s[16 * w + lr][kt * 32 + lg * 8];
#pragma unroll
        for (int nt = 0; nt < 16; ++nt) {
            short8 b = pw2v[(kt * 16 + nt) * 64 + l];
            acc2[nt] = __builtin_amdgcn_mfma_f32_16x16x32_bf16(a, b, acc2[nt], 0, 0, 0);
        }
    }
#pragma unroll
    for (int nt = 0; nt < 16; ++nt) {
        int col = nt * 16 + lr;
        float bb = b2[col];
#pragma unroll
        for (int r = 0; r < 4; ++r) {
            float v = fmaxf(acc2[nt][r] + bb, 0.f);
            h[(size_t)(m0 + 16 * w + lg * 4 + r) * 256 + col] = bf16rne(v);
        }
    }
}

// ---------------------------------------------------------------------------
// InstanceNorm stats (bf16 h), two-phase, folded affine.
// ---------------------------------------------------------------------------
#define NCHUNK 25
#define CHUNK (NN / NCHUNK)

__global__ __launch_bounds__(256) void stats_partial(
    const unsigned short* __restrict__ h, float* __restrict__ part)
{
    const int b = blockIdx.x, ch = blockIdx.y, c = threadIdx.x;
    const unsigned short* base = h + ((size_t)b * NN + (size_t)ch * CHUNK) * 256 + c;
    float s = 0.f, s2 = 0.f;
    for (int n = 0; n < CHUNK; ++n) {
        float v = bf2f(base[(size_t)n * 256]);
        s += v;
        s2 += v * v;
    }
    size_t o = (((size_t)b * NCHUNK + ch) * 256 + c) * 2;
    part[o] = s;
    part[o + 1] = s2;
}

__global__ __launch_bounds__(256) void stats_final(
    const float* __restrict__ part, const float* __restrict__ gamma,
    const float* __restrict__ beta, float* __restrict__ scv,
    float* __restrict__ shv)
{
    const int b = blockIdx.x, c = threadIdx.x;
    float s = 0.f, s2 = 0.f;
    for (int ch = 0; ch < NCHUNK; ++ch) {
        size_t o = (((size_t)b * NCHUNK + ch) * 256 + c) * 2;
        s += part[o];
        s2 += part[o + 1];
    }
    const float inv = 1.0f / (float)NN;
    float mean = s * inv;
    float var = s2 * inv - mean * mean;
    float rs = rsqrtf(var + 1e-5f);
    float sc = gamma[c] * rs;
    scv[b * 256 + c] = sc;
    shv[b * 256 + c] = beta[c] - mean * sc;
}

// ---------------------------------------------------------------------------
// Kernel 3: fused layers 3+4 + PENALTY fill + scatter. Block = 64 rows.
// ---------------------------------------------------------------------------
__global__ __launch_bounds__(256) void fused34_mfma(
    const unsigned short* __restrict__ h, const unsigned short* __restrict__ pw3,
    const float* __restrict__ b3, const unsigned short* __restrict__ pw4,
    const float* __restrict__ b4, const float* __restrict__ scv,
    const float* __restrict__ shv, const float* __restrict__ sdist,
    const int* __restrict__ idxb, float* __restrict__ out)
{
    __shared__ unsigned short c1s[64][136];
    const int t = threadIdx.x;
    const int w = t >> 6, l = t & 63;
    const int m0 = blockIdx.x * 64;
    const int lr = l & 15, lg = l >> 4;

    {
        float4* o4 = (float4*)(out + (size_t)m0 * VV);
        const float4 pv = make_float4(PENALTY, PENALTY, PENALTY, PENALTY);
        for (int i = t; i < 64 * VV / 4; i += 256) o4[i] = pv;
    }

    const int myrow = m0 + 16 * w + lr;
    const int mybatch = myrow / NN;

    f32x4 acc[8] = {};
    const short8* hrow = (const short8*)(h + (size_t)myrow * 256);
    const short8* pw3v = (const short8*)pw3;
#pragma unroll
    for (int kt = 0; kt < 8; ++kt) {
        int k0 = kt * 32 + lg * 8;
        short8 hv = hrow[kt * 4 + lg];
        const float4* scp = (const float4*)(scv + mybatch * 256 + k0);
        const float4* shp = (const float4*)(shv + mybatch * 256 + k0);
        float4 sc0 = scp[0], sc1 = scp[1];
        float4 sh0 = shp[0], sh1 = shp[1];
        short8 a;
        a[0] = (short)bf16rne(fmaf(bf2f((unsigned short)hv[0]), sc0.x, sh0.x));
        a[1] = (short)bf16rne(fmaf(bf2f((unsigned short)hv[1]), sc0.y, sh0.y));
        a[2] = (short)bf16rne(fmaf(bf2f((unsigned short)hv[2]), sc0.z, sh0.z));
        a[3] = (short)bf16rne(fmaf(bf2f((unsigned short)hv[3]), sc0.w, sh0.w));
        a[4] = (short)bf16rne(fmaf(bf2f((unsigned short)hv[4]), sc1.x, sh1.x));
        a[5] = (short)bf16rne(fmaf(bf2f((unsigned short)hv[5]), sc1.y, sh1.y));
        a[6] = (short)bf16rne(fmaf(bf2f((unsigned short)hv[6]), sc1.z, sh1.z));
        a[7] = (short)bf16rne(fmaf(bf2f((unsigned short)hv[7]), sc1.w, sh1.w));
#pragma unroll
        for (int nt = 0; nt < 8; ++nt) {
            short8 b = pw3v[(kt * 8 + nt) * 64 + l];
            acc[nt] = __builtin_amdgcn_mfma_f32_16x16x32_bf16(a, b, acc[nt], 0, 0, 0);
        }
    }
#pragma unroll
    for (int nt = 0; nt < 8; ++nt) {
        int col = nt * 16 + lr;
        float bb = b3[col];
#pragma unroll
        for (int r = 0; r < 4; ++r) {
            float v = fmaxf(acc[nt][r] + bb, 0.f);
            c1s[16 * w + lg * 4 + r][col] = bf16rne(v);
        }
    }
    __syncthreads();

    f32x4 acc2[7] = {};
    const short8* pw4v = (const short8*)pw4;
#pragma unroll
    for (int kt = 0; kt < 4; ++kt) {
        short8 a = *(const short8*)&c1s[16 * w + lr][kt * 32 + lg * 8];
#pragma unroll
        for (int nt = 0; nt < 7; ++nt) {
            short8 b = pw4v[(kt * 7 + nt) * 64 + l];
            acc2[nt] = __builtin_amdgcn_mfma_f32_16x16x32_bf16(a, b, acc2[nt], 0, 0, 0);
        }
    }
#pragma unroll
    for (int nt = 0; nt < 7; ++nt) {
        int col = nt * 16 + lr;
        if (col < KK) {
            float bb = b4[col];
#pragma unroll
            for (int r = 0; r < 4; ++r) {
                int mrow = m0 + 16 * w + lg * 4 + r;
                float v = acc2[nt][r] + bb - sdist[(size_t)mrow * KK + col];
                int id = idxb[(size_t)mrow * KK + col];
                out[(size_t)mrow * VV + id] = v;
            }
        }
    }
}

extern "C" void kernel_launch(void* const* d_in, const int* in_sizes, int n_in,
                              void* d_out, int out_size, void* d_ws, size_t ws_size,
                              hipStream_t stream)
{
    const float* dist  = (const float*)d_in[0];
    const float* theta = (const float*)d_in[1];
    const float* scale = (const float*)d_in[2];
    const float* w1 = (const float*)d_in[3];
    const float* b1 = (const float*)d_in[4];
    const float* w2 = (const float*)d_in[5];
    const float* b2 = (const float*)d_in[6];
    const float* w3 = (const float*)d_in[7];
    const float* b3 = (const float*)d_in[8];
    const float* w4 = (const float*)d_in[9];
    const float* b4 = (const float*)d_in[10];
    const float* gamma = (const float*)d_in[11];
    const float* beta  = (const float*)d_in[12];
    float* out = (float*)d_out;

    const int M = BB * NN;  // 16000

    char* p = (char*)d_ws;
    unsigned short* xin = (unsigned short*)p;       p += (size_t)M * XPAD * 2;
    unsigned short* h   = (unsigned short*)p;       p += (size_t)M * 256 * 2;
    float* sdist = (float*)p;                       p += (size_t)M * KK * 4;
    int*   idxb  = (int*)p;                         p += (size_t)M * KK * 4;
    float* part  = (float*)p;                       p += (size_t)BB * NCHUNK * 256 * 2 * 4;
    float* scv   = (float*)p;                       p += 8 * 256 * 4;
    float* shv   = (float*)p;                       p += 8 * 256 * 4;
    unsigned short* pw1 = (unsigned short*)p;       p += 56 * 512 * 2;
    unsigned short* pw2 = (unsigned short*)p;       p += 64 * 512 * 2;
    unsigned short* pw3 = (unsigned short*)p;       p += 64 * 512 * 2;
    unsigned short* pw4 = (unsigned short*)p;       p += 28 * 512 * 2;

    wpack_kernel<<<212, 256, 0, stream>>>(w1, w2, w3, w4, pw1, pw2, pw3, pw4);

    topk_kernel<<<M, 256, 0, stream>>>(dist, theta, scale, xin, sdist, idxb);

    fused12_mfma<<<M / 64, 256, 0, stream>>>(xin, pw1, b1, pw2, b2, h);

    stats_partial<<<dim3(BB, NCHUNK), 256, 0, stream>>>(h, part);
    stats_final<<<BB, 256, 0, stream>>>(part, gamma, beta, scv, shv);

    fused34_mfma<<<M / 64, 256, 0, stream>>>(h, pw3, b3, pw4, b4, scv, shv,
                                             sdist, idxb, out);
}